// Round 5
// baseline (68.636 us; speedup 1.0000x reference)
//
#include <hip/hip_runtime.h>
#include <math.h>

#define N_ROWS 8192
#define N_NEG 16
#define NBLK (N_ROWS / 8)   // 1024 main-kernel blocks

__device__ __forceinline__ float log_sigmoid(float v) {
    // log(sigmoid(v)) = min(v,0) - log1p(exp(-|v|))  (numerically stable)
    return fminf(v, 0.0f) - log1pf(__expf(-fabsf(v)));
}

// Distributed top-16 insert: lanes 0..15 hold the sorted-descending list.
// cand and tau are wave-uniform. ~1 cross-lane DS op per insert.
#define INSERT(mv)                                                          \
    {                                                                       \
        unsigned long long ball = __ballot((mv) > tau);                     \
        while (ball) {                                                      \
            const int src = __ffsll((unsigned long long)ball) - 1;          \
            const float cand = __shfl((mv), src);                           \
            ball &= ball - 1;                                               \
            if (cand > tau) {                                               \
                float tprev = __shfl_up(t, 1);                              \
                if (lane == 0) tprev = 3.0e38f;                             \
                t = (t >= cand) ? t : (tprev >= cand ? cand : tprev);       \
                tau = __shfl(t, 15);                                        \
                ball &= __ballot((mv) > tau); /* prune vs new tau */        \
            }                                                               \
        }                                                                   \
    }

// Process one 512-float chunk given its two register float4s.
// Exact gate: once tau>=0, raw>tau <=> masked>tau (mask only writes 0);
// while tau<0 the gate fires trivially -> still exact.
#define PROCESS(ci, v0, v1)                                                 \
    {                                                                       \
        const float mxv = fmaxf(fmaxf(fmaxf((v0).x, (v0).y), (v0).z),       \
                          fmaxf(fmaxf(fmaxf((v0).w, (v1).x), (v1).y),       \
                                fmaxf((v1).z, (v1).w)));                    \
        if (__any(mxv > tau)) {                                             \
            const int base = ((ci) << 9) + (lane << 2);                     \
            const int4 s0 = *reinterpret_cast<const int4*>(&sel_lds[base]); \
            const int4 s1 =                                                 \
                *reinterpret_cast<const int4*>(&sel_lds[base + 256]);       \
            const float m0 = (s0.x != seli) ? (v0).x : 0.0f;                \
            const float m1 = (s0.y != seli) ? (v0).y : 0.0f;                \
            const float m2 = (s0.z != seli) ? (v0).z : 0.0f;                \
            const float m3 = (s0.w != seli) ? (v0).w : 0.0f;                \
            const float m4 = (s1.x != seli) ? (v1).x : 0.0f;                \
            const float m5 = (s1.y != seli) ? (v1).y : 0.0f;                \
            const float m6 = (s1.z != seli) ? (v1).z : 0.0f;                \
            const float m7 = (s1.w != seli) ? (v1).w : 0.0f;                \
            INSERT(m0); INSERT(m1); INSERT(m2); INSERT(m3);                 \
            INSERT(m4); INSERT(m5); INSERT(m6); INSERT(m7);                 \
        }                                                                   \
    }

// 8 waves per block, one row per wave. sel staged in LDS. Named-buffer
// 2-deep pipeline (512-float chunks). No atomics: partial -> d_ws.
__global__ __launch_bounds__(512) void nsl_topk_kernel(
        const float* __restrict__ x,
        const int*   __restrict__ sel,
        float*       __restrict__ ws) {
    __shared__ int   sel_lds[N_ROWS];
    __shared__ float partial[8];

    // cooperative stage of the full sel vector (32 KB), coalesced int4
    {
        const int4* s4 = reinterpret_cast<const int4*>(sel);
        int4*       d4 = reinterpret_cast<int4*>(sel_lds);
#pragma unroll
        for (int k = 0; k < 4; ++k)
            d4[k * 512 + threadIdx.x] = s4[k * 512 + threadIdx.x];
    }
    __syncthreads();

    const int lane = threadIdx.x & 63;
    const int wid  = threadIdx.x >> 6;
    const int row  = (blockIdx.x << 3) + wid;

    const int    seli = sel_lds[row];
    const float* xrow = x + (size_t)row * N_ROWS;
    const float* pw   = xrow + (lane << 2);   // lane's float4 within 1 KB half

    float t   = -3.0e38f;   // this lane's slot of the distributed top-16
    float tau = -3.0e38f;   // current 16th-largest (uniform)

    // chunk c = floats [c*512, c*512+511]; halves at +0 and +256 floats.
#define LOADQ(c, h) *reinterpret_cast<const float4*>(pw + ((c) << 9) + ((h) << 8))

    float4 A0 = LOADQ(0, 0), A1 = LOADQ(0, 1);
    float4 B0 = LOADQ(1, 0), B1 = LOADQ(1, 1);

#pragma unroll 1
    for (int i = 0; i < 16; i += 2) {
        const float4 vA0 = A0, vA1 = A1;
        const int na = (i + 2) & 15;          // wrap: tail reloads are L1 hits
        A0 = LOADQ(na, 0); A1 = LOADQ(na, 1);
        PROCESS(i, vA0, vA1);

        const float4 vB0 = B0, vB1 = B1;
        const int nb = (i + 3) & 15;
        B0 = LOADQ(nb, 0); B1 = LOADQ(nb, 1);
        PROCESS(i + 1, vB0, vB1);
    }
#undef LOADQ

    // negsum over the 16 kept values (lanes 0..15), xor-reduce in-group
    float ls = (lane < 16) ? log_sigmoid(-t) : 0.0f;
    ls += __shfl_xor(ls, 8);
    ls += __shfl_xor(ls, 4);
    ls += __shfl_xor(ls, 2);
    ls += __shfl_xor(ls, 1);

    if (lane == 0) {
        const float d = xrow[row];                      // raw diagonal score
        partial[wid] = -log_sigmoid(d) * (1.0f / (float)N_ROWS)
                       - ls * (1.0f / ((float)N_ROWS * (float)N_NEG));
    }
    __syncthreads();

    if (threadIdx.x == 0) {
        float s = 0.0f;
#pragma unroll
        for (int w = 0; w < 8; ++w) s += partial[w];
        ws[blockIdx.x] = s;                             // plain store, no atomic
    }
}

// single-block final reduce: 1024 partials -> d_out[0]
__global__ __launch_bounds__(256) void nsl_reduce_kernel(
        const float* __restrict__ ws, float* __restrict__ out) {
    __shared__ float red[4];
    float s = 0.0f;
#pragma unroll
    for (int k = 0; k < NBLK / 256; ++k) s += ws[k * 256 + threadIdx.x];
    s += __shfl_xor(s, 32);
    s += __shfl_xor(s, 16);
    s += __shfl_xor(s, 8);
    s += __shfl_xor(s, 4);
    s += __shfl_xor(s, 2);
    s += __shfl_xor(s, 1);
    const int lane = threadIdx.x & 63, wid = threadIdx.x >> 6;
    if (lane == 0) red[wid] = s;
    __syncthreads();
    if (threadIdx.x == 0)
        out[0] = red[0] + red[1] + red[2] + red[3];
}

extern "C" void kernel_launch(void* const* d_in, const int* in_sizes, int n_in,
                              void* d_out, int out_size, void* d_ws, size_t ws_size,
                              hipStream_t stream) {
    const float* x   = (const float*)d_in[0];
    const int*   sel = (const int*)d_in[1];
    float* out = (float*)d_out;
    float* ws  = (float*)d_ws;

    nsl_topk_kernel<<<dim3(NBLK), dim3(512), 0, stream>>>(x, sel, ws);
    nsl_reduce_kernel<<<dim3(1), dim3(256), 0, stream>>>(ws, out);
}